// Round 5
// baseline (293.057 us; speedup 1.0000x reference)
//
#include <hip/hip_runtime.h>
#include <hip/hip_bf16.h>
#include <math.h>

#define B_ 4
#define T_ 2048
#define D_ 1024
#define H_ 16
#define HD_ 64

typedef _Float16 f16x8 __attribute__((ext_vector_type(8)));
typedef _Float16 f16x4 __attribute__((ext_vector_type(4)));
typedef float f32x4 __attribute__((ext_vector_type(4)));

// async global->LDS, 16 B per lane, dest = wave-uniform base + lane*16
__device__ __forceinline__ void gload_lds16(const _Float16* g, _Float16* l) {
    __builtin_amdgcn_global_load_lds(
        (const __attribute__((address_space(1))) void*)g,
        (__attribute__((address_space(3))) void*)l,
        16, 0, 0);
}

// ---------------------------------------------------------------------------
// fp32 -> fp16 cast, 4 elems/thread
// ---------------------------------------------------------------------------
__global__ __launch_bounds__(256) void castf(const float* __restrict__ in,
                                             _Float16* __restrict__ out, int n4) {
    const int i = blockIdx.x * 256 + threadIdx.x;
    if (i < n4) {
        const float4 v = ((const float4*)in)[i];
        f16x4 h = {(_Float16)v.x, (_Float16)v.y, (_Float16)v.z, (_Float16)v.w};
        ((f16x4*)out)[i] = h;
    }
}

// fused 4-weight cast: grid.z selects which weight
__global__ __launch_bounds__(256) void castw(const float* __restrict__ a,
                                             const float* __restrict__ b,
                                             const float* __restrict__ c,
                                             const float* __restrict__ d,
                                             _Float16* __restrict__ oa,
                                             _Float16* __restrict__ ob,
                                             _Float16* __restrict__ oc,
                                             _Float16* __restrict__ od) {
    const int z = blockIdx.z;
    const float* in = (z == 0) ? a : (z == 1 ? b : (z == 2 ? c : d));
    _Float16* out = (z == 0) ? oa : (z == 1 ? ob : (z == 2 ? oc : od));
    const int i = blockIdx.x * 256 + threadIdx.x;
    const float4 v = ((const float4*)in)[i];
    f16x4 h = {(_Float16)v.x, (_Float16)v.y, (_Float16)v.z, (_Float16)v.w};
    ((f16x4*)out)[i] = h;
}

// ---------------------------------------------------------------------------
// Fused QKV GEMM + rmsnorm/rotary epilogue (m97 structure).
// z=0: rms+rotary+0.125*log2e -> qh ; z=1: rms+rotary -> kh ;
// z=2: plain -> vt transposed [b][h][d][T]
// ---------------------------------------------------------------------------
__global__ __launch_bounds__(256) void gemm_qkv(const _Float16* __restrict__ A,
                                                const _Float16* __restrict__ Wq,
                                                const _Float16* __restrict__ Wk,
                                                const _Float16* __restrict__ Wv,
                                                _Float16* __restrict__ qh,
                                                _Float16* __restrict__ kh,
                                                _Float16* __restrict__ vt) {
    constexpr int K = D_;
    const int z = blockIdx.z;
    const _Float16* W = (z == 0) ? Wq : (z == 1 ? Wk : Wv);
    __shared__ _Float16 As[128 * 32];
    __shared__ _Float16 Bs[128 * 32];
    const int tid = threadIdx.x;
    const int lane = tid & 63, w = tid >> 6;
    const int col = lane & 15, quad = lane >> 4;
    const int wm = w >> 1, wn = w & 1;
    const int row0 = blockIdx.y * 128, col0 = blockIdx.x * 128;
    const int sr = lane >> 2, sc = (lane & 3) * 8;

    f32x4 acc[4][4];
#pragma unroll
    for (int i = 0; i < 4; ++i)
#pragma unroll
        for (int j = 0; j < 4; ++j) acc[i][j] = (f32x4){0.f, 0.f, 0.f, 0.f};

    for (int kt = 0; kt < K / 32; ++kt) {
        const int k0 = kt * 32;
#pragma unroll
        for (int it = 0; it < 2; ++it) {
            const int rb = it * 64 + w * 16;
            gload_lds16(A + (size_t)(row0 + rb + sr) * K + k0 + sc, As + rb * 32);
            gload_lds16(W + (size_t)(col0 + rb + sr) * K + k0 + sc, Bs + rb * 32);
        }
        __syncthreads();
        f16x8 af[4], bf[4];
#pragma unroll
        for (int i = 0; i < 4; ++i) {
            af[i] = *(const f16x8*)&As[(wm * 64 + i * 16 + col) * 32 + quad * 8];
            bf[i] = *(const f16x8*)&Bs[(wn * 64 + i * 16 + col) * 32 + quad * 8];
        }
#pragma unroll
        for (int mi = 0; mi < 4; ++mi)
#pragma unroll
            for (int ni = 0; ni < 4; ++ni)
                acc[mi][ni] = __builtin_amdgcn_mfma_f32_16x16x32_f16(af[mi], bf[ni],
                                                                     acc[mi][ni], 0, 0, 0);
        __syncthreads();
    }

    if (z < 2) {
        _Float16* C = (z == 0) ? qh : kh;
        const float qscale = (z == 0) ? 0.18033688011112042f : 1.0f;  // 0.125*log2(e)
        const float fr = exp2f(-10.0f * (float)col * (1.0f / 15.0f));
#pragma unroll
        for (int mi = 0; mi < 4; ++mi) {
            float ssq[4];
#pragma unroll
            for (int r = 0; r < 4; ++r) {
                float t = 0.f;
#pragma unroll
                for (int ni = 0; ni < 4; ++ni) t += acc[mi][ni][r] * acc[mi][ni][r];
                ssq[r] = t;
            }
#pragma unroll
            for (int st = 1; st < 16; st <<= 1)
#pragma unroll
                for (int r = 0; r < 4; ++r) ssq[r] += __shfl_xor(ssq[r], st, 64);
            const int rowb = row0 + wm * 64 + mi * 16 + quad * 4;
#pragma unroll
            for (int r = 0; r < 4; ++r) {
                const float scl = rsqrtf(ssq[r] * (1.0f / 64.0f) + 1e-6f) * qscale;
                const int t = (rowb + r) & (T_ - 1);
                float s, c;
                sincosf((float)t * fr, &s, &c);
                const float x0 = acc[mi][0][r] * scl;
                const float x1 = acc[mi][1][r] * scl;
                const float x2 = acc[mi][2][r] * scl;
                const float x3 = acc[mi][3][r] * scl;
                const float y0 = fmaf(x0, c, x2 * s);
                const float y2 = fmaf(x2, c, -x0 * s);
                const size_t base = (size_t)(rowb + r) * D_ + col0 + wn * 64 + col;
                C[base + 0]  = (_Float16)y0;
                C[base + 16] = (_Float16)x1;
                C[base + 32] = (_Float16)y2;
                C[base + 48] = (_Float16)x3;
            }
        }
    } else {
        const int hh = blockIdx.x * 2 + wn;
#pragma unroll
        for (int mi = 0; mi < 4; ++mi) {
            const int row = row0 + wm * 64 + mi * 16 + quad * 4;
            const int bb = row >> 11;
            const int t0m = row & (T_ - 1);
#pragma unroll
            for (int ni = 0; ni < 4; ++ni) {
                const int d = ni * 16 + col;
                f16x4 pk = {(_Float16)acc[mi][ni][0], (_Float16)acc[mi][ni][1],
                            (_Float16)acc[mi][ni][2], (_Float16)acc[mi][ni][3]};
                *(f16x4*)&vt[((size_t)(bb * H_ + hh) * HD_ + d) * T_ + t0m] = pk;
            }
        }
    }
}

// ---------------------------------------------------------------------------
// WO GEMM: out[M,N] = A[M,K] @ W[N,K]^T, fp16 in, fp32 out. m97 structure.
// ---------------------------------------------------------------------------
__global__ __launch_bounds__(256) void gemm_wo(const _Float16* __restrict__ A,
                                               const _Float16* __restrict__ W,
                                               float* __restrict__ C) {
    constexpr int K = D_, N = D_;
    __shared__ _Float16 As[128 * 32];
    __shared__ _Float16 Bs[128 * 32];
    const int tid = threadIdx.x;
    const int lane = tid & 63, w = tid >> 6;
    const int col = lane & 15, quad = lane >> 4;
    const int wm = w >> 1, wn = w & 1;
    const int row0 = blockIdx.y * 128, col0 = blockIdx.x * 128;
    const int sr = lane >> 2, sc = (lane & 3) * 8;

    f32x4 acc[4][4];
#pragma unroll
    for (int i = 0; i < 4; ++i)
#pragma unroll
        for (int j = 0; j < 4; ++j) acc[i][j] = (f32x4){0.f, 0.f, 0.f, 0.f};

    for (int kt = 0; kt < K / 32; ++kt) {
        const int k0 = kt * 32;
#pragma unroll
        for (int it = 0; it < 2; ++it) {
            const int rb = it * 64 + w * 16;
            gload_lds16(A + (size_t)(row0 + rb + sr) * K + k0 + sc, As + rb * 32);
            gload_lds16(W + (size_t)(col0 + rb + sr) * K + k0 + sc, Bs + rb * 32);
        }
        __syncthreads();
        f16x8 af[4], bf[4];
#pragma unroll
        for (int i = 0; i < 4; ++i) {
            af[i] = *(const f16x8*)&As[(wm * 64 + i * 16 + col) * 32 + quad * 8];
            bf[i] = *(const f16x8*)&Bs[(wn * 64 + i * 16 + col) * 32 + quad * 8];
        }
#pragma unroll
        for (int mi = 0; mi < 4; ++mi)
#pragma unroll
            for (int ni = 0; ni < 4; ++ni)
                acc[mi][ni] = __builtin_amdgcn_mfma_f32_16x16x32_f16(af[mi], bf[ni],
                                                                     acc[mi][ni], 0, 0, 0);
        __syncthreads();
    }
#pragma unroll
    for (int mi = 0; mi < 4; ++mi)
#pragma unroll
        for (int ni = 0; ni < 4; ++ni)
#pragma unroll
            for (int r = 0; r < 4; ++r)
                C[(size_t)(row0 + wm * 64 + mi * 16 + quad * 4 + r) * N +
                  col0 + wn * 64 + ni * 16 + col] = acc[mi][ni][r];
}

// ---------------------------------------------------------------------------
// MFMA flash attention (fp16 in/out).
// ROUND 5: 32 q per wave (two 16-q groups A/B), 4 waves x 256 thr, 128 q
// per block per phase (grid unchanged: (64 bh, 8 pair), diagonal pairing,
// nkt = 2qt+2). Rationale: flash is LDS-read-throughput-bound — old
// structure issued 18 ds_read_b128 per 16 MFMA per wave per tile (per-CU
// LDS-pipe time ~3.4x the MFMA time at 85 B/cyc). K- and V-fragments are
// q-independent: reading them ONCE and feeding two Q/P operand sets gives
// 20 reads per 32 MFMA (per-block LDS traffic per tile 144 -> 80 b128,
// -44%) for identical FLOPs. LDS 54.5 KB -> 2 blocks/CU = 8 waves/CU
// (same as before). Dbuf staging + single vmcnt(0)+s_barrier per tile
// retained from round 4 (verified). Staging: 256 thr x 16 B = 32 rows per
// gload -> 2 calls per K/V tile buffer.
// ---------------------------------------------------------------------------
#define LDP 88

__global__ __launch_bounds__(256) void flash_mfma(const _Float16* __restrict__ qh,
                                                  const _Float16* __restrict__ kh,
                                                  const _Float16* __restrict__ vt,
                                                  _Float16* __restrict__ o) {
    __shared__ _Float16 Kl[2][64 * 64];
    __shared__ _Float16 Vl[2][64 * 64];
    __shared__ _Float16 Pl[4][2][16 * LDP];
    const int tid = threadIdx.x;
    const int lane = tid & 63, w = tid >> 6;           // w in [0,4)
    const int col = lane & 15, quad = lane >> 4;
    const int bh = blockIdx.x, b = bh >> 4, h = bh & 15;
    const int srow = lane >> 3;                        // row-in-8 for staging
    const int schunk = (lane & 7) ^ srow;              // global-side swizzle
    const int sw = col & 7;                            // read-side swizzle key
    const int r1 = w * 8 + srow;                       // staged rows 0..31
    const int r2 = 32 + w * 8 + srow;                  // staged rows 32..63

    const _Float16* kbase = kh + ((size_t)b * T_ * H_ + (size_t)h) * HD_;
    const _Float16* vbase = vt + ((size_t)(b * H_ + h)) * (size_t)HD_ * T_;

// stage one 64-key K/V tile into buf: 4 gloads (2 K rows-halves, 2 V d-halves)
#define STAGE_KV(buf, kk)                                                           \
    gload_lds16(kbase + (size_t)((kk) + r1) * (H_ * HD_) + schunk * 8,              \
                &Kl[buf][(w * 8) * 64]);                                            \
    gload_lds16(kbase + (size_t)((kk) + r2) * (H_ * HD_) + schunk * 8,              \
                &Kl[buf][(32 + w * 8) * 64]);                                       \
    gload_lds16(vbase + (size_t)r1 * T_ + (kk) + schunk * 8,                        \
                &Vl[buf][(w * 8) * 64]);                                            \
    gload_lds16(vbase + (size_t)r2 * T_ + (kk) + schunk * 8,                        \
                &Vl[buf][(32 + w * 8) * 64])

    for (int phase = 0; phase < 2; ++phase) {
        const int qt = (phase == 0) ? (int)blockIdx.y : (15 - (int)blockIdx.y);
        const int q0 = qt * 128;
        const int qw = q0 + w * 32;   // this wave's q base (32 rows)

        // Q as B-operand, two groups: lane holds Q[qw(+16g)+col][quad*8+j (+32)]
        const _Float16* qpA = qh + ((size_t)(b * T_ + qw + col) * H_ + h) * HD_ + quad * 8;
        const _Float16* qpB = qh + ((size_t)(b * T_ + qw + 16 + col) * H_ + h) * HD_ + quad * 8;
        const f16x8 qA0 = *(const f16x8*)(qpA), qA1 = *(const f16x8*)(qpA + 32);
        const f16x8 qB0 = *(const f16x8*)(qpB), qB1 = *(const f16x8*)(qpB + 32);

        f32x4 oa0[4], oa1[4];
#pragma unroll
        for (int i = 0; i < 4; ++i) {
            oa0[i] = (f32x4){0.f, 0.f, 0.f, 0.f};
            oa1[i] = (f32x4){0.f, 0.f, 0.f, 0.f};
        }
        float l0 = 0.f, l1 = 0.f;  // per-lane partial denoms (q = col of group)

        const int nkt = 2 * qt + 2;

        // ---- prologue: stage tile 0 -> buf 0, full drain ----
        STAGE_KV(0, 0);
        __builtin_amdgcn_sched_barrier(0);
        asm volatile("s_waitcnt vmcnt(0)" ::: "memory");
        __builtin_amdgcn_sched_barrier(0);
        __builtin_amdgcn_s_barrier();

        for (int kt = 0; kt < nkt; ++kt) {
            const int k0 = kt * 64;
            const int cur = kt & 1;

            // ---- issue next tile's stage early (hides under compute) ----
            if (kt + 1 < nkt) {
                STAGE_KV(cur ^ 1, k0 + 64);
            }

            // ---- S^T[key][q] both groups: A = K rows (read once) ----
            f32x4 s0[4], s1[4];
            __builtin_amdgcn_s_setprio(1);
#pragma unroll
            for (int tn = 0; tn < 4; ++tn) {
                const _Float16* kp = &Kl[cur][(tn * 16 + col) * 64];
                const f16x8 kA0 = *(const f16x8*)(kp + ((quad ^ sw) << 3));
                const f16x8 kA1 = *(const f16x8*)(kp + (((quad | 4) ^ sw) << 3));
                f32x4 a = (f32x4){0.f, 0.f, 0.f, 0.f};
                a = __builtin_amdgcn_mfma_f32_16x16x32_f16(kA0, qA0, a, 0, 0, 0);
                a = __builtin_amdgcn_mfma_f32_16x16x32_f16(kA1, qA1, a, 0, 0, 0);
                s0[tn] = a;
                f32x4 bb = (f32x4){0.f, 0.f, 0.f, 0.f};
                bb = __builtin_amdgcn_mfma_f32_16x16x32_f16(kA0, qB0, bb, 0, 0, 0);
                bb = __builtin_amdgcn_mfma_f32_16x16x32_f16(kA1, qB1, bb, 0, 0, 0);
                s1[tn] = bb;
            }
            __builtin_amdgcn_s_setprio(0);

            // ---- causal masks per group ----
            if (k0 + 63 > qw) {
                const int qq = qw + col;
#pragma unroll
                for (int tn = 0; tn < 4; ++tn)
#pragma unroll
                    for (int r = 0; r < 4; ++r) {
                        const int key = k0 + tn * 16 + quad * 4 + r;
                        if (key > qq) s0[tn][r] = -1e30f;
                    }
            }
            if (k0 + 63 > qw + 16) {
                const int qq = qw + 16 + col;
#pragma unroll
                for (int tn = 0; tn < 4; ++tn)
#pragma unroll
                    for (int r = 0; r < 4; ++r) {
                        const int key = k0 + tn * 16 + quad * 4 + r;
                        if (key > qq) s1[tn][r] = -1e30f;
                    }
            }

            // ---- p = exp2(s); l accumulate; packed P stores ----
#pragma unroll
            for (int tn = 0; tn < 4; ++tn) {
                f16x4 pk0, pk1;
#pragma unroll
                for (int r = 0; r < 4; ++r) {
                    const float p0 = exp2f(s0[tn][r]);
                    l0 += p0;
                    pk0[r] = (_Float16)p0;
                    const float p1 = exp2f(s1[tn][r]);
                    l1 += p1;
                    pk1[r] = (_Float16)p1;
                }
                *(f16x4*)&Pl[w][0][col * LDP + tn * 16 + quad * 4] = pk0;
                *(f16x4*)&Pl[w][1][col * LDP + tn * 16 + quad * 4] = pk1;
            }

            // ---- O[q][d] += P @ V, V-fragments read once for both groups ----
            const f16x8 pA0a = *(const f16x8*)&Pl[w][0][col * LDP + quad * 8];
            const f16x8 pA1a = *(const f16x8*)&Pl[w][0][col * LDP + quad * 8 + 32];
            const f16x8 pA0b = *(const f16x8*)&Pl[w][1][col * LDP + quad * 8];
            const f16x8 pA1b = *(const f16x8*)&Pl[w][1][col * LDP + quad * 8 + 32];
            __builtin_amdgcn_s_setprio(1);
#pragma unroll
            for (int tn = 0; tn < 4; ++tn) {
                const _Float16* vp = &Vl[cur][(tn * 16 + col) * 64];
                const f16x8 vB0 = *(const f16x8*)(vp + ((quad ^ sw) << 3));
                const f16x8 vB1 = *(const f16x8*)(vp + (((quad | 4) ^ sw) << 3));
                oa0[tn] = __builtin_amdgcn_mfma_f32_16x16x32_f16(pA0a, vB0, oa0[tn], 0, 0, 0);
                oa0[tn] = __builtin_amdgcn_mfma_f32_16x16x32_f16(pA1a, vB1, oa0[tn], 0, 0, 0);
                oa1[tn] = __builtin_amdgcn_mfma_f32_16x16x32_f16(pA0b, vB0, oa1[tn], 0, 0, 0);
                oa1[tn] = __builtin_amdgcn_mfma_f32_16x16x32_f16(pA1b, vB1, oa1[tn], 0, 0, 0);
            }
            __builtin_amdgcn_s_setprio(0);

            // ---- single per-tile sync: next tile landed + all waves done ----
            __builtin_amdgcn_sched_barrier(0);
            asm volatile("s_waitcnt vmcnt(0)" ::: "memory");
            __builtin_amdgcn_sched_barrier(0);
            __builtin_amdgcn_s_barrier();
        }

        // ---- finish l per group, redistribute, write both q groups ----
        l0 += __shfl_xor(l0, 16, 64);
        l0 += __shfl_xor(l0, 32, 64);
        l1 += __shfl_xor(l1, 16, 64);
        l1 += __shfl_xor(l1, 32, 64);
        const float linv0 = 1.0f / l0;
        const float linv1 = 1.0f / l1;
        float inv0[4], inv1[4];
#pragma unroll
        for (int r = 0; r < 4; ++r) {
            inv0[r] = __shfl(linv0, quad * 4 + r, 64);
            inv1[r] = __shfl(linv1, quad * 4 + r, 64);
        }
#pragma unroll
        for (int tn = 0; tn < 4; ++tn)
#pragma unroll
            for (int r = 0; r < 4; ++r) {
                o[((size_t)(b * T_ + qw + quad * 4 + r) * H_ + h) * HD_ + tn * 16 + col] =
                    (_Float16)(oa0[tn][r] * inv0[r]);
                o[((size_t)(b * T_ + qw + 16 + quad * 4 + r) * H_ + h) * HD_ + tn * 16 + col] =
                    (_Float16)(oa1[tn][r] * inv1[r]);
            }
    }
#undef STAGE_KV
}

// ---------------------------------------------------------------------------
extern "C" void kernel_launch(void* const* d_in, const int* in_sizes, int n_in,
                              void* d_out, int out_size, void* d_ws, size_t ws_size,
                              hipStream_t stream) {
    const float* x  = (const float*)d_in[0];
    const float* wq = (const float*)d_in[1];
    const float* wk = (const float*)d_in[2];
    const float* wv = (const float*)d_in[3];
    const float* wo = (const float*)d_in[4];
    float* out = (float*)d_out;

    const size_t NE = (size_t)B_ * T_ * D_;   // 8,388,608
    const size_t WE = (size_t)D_ * D_;        // 1,048,576
    _Float16* xh  = (_Float16*)d_ws;
    _Float16* qh  = xh + NE;
    _Float16* kh  = qh + NE;
    _Float16* vth = kh + NE;
    _Float16* oh  = vth + NE;
    _Float16* wqh = oh + NE;
    _Float16* wkh = wqh + WE;
    _Float16* wvh = wkh + WE;
    _Float16* woh = wvh + WE;

    castf<<<NE / 1024, 256, 0, stream>>>(x, xh, (int)(NE / 4));
    castw<<<dim3(WE / 1024, 1, 4), 256, 0, stream>>>(wq, wk, wv, wo,
                                                     wqh, wkh, wvh, woh);

    gemm_qkv<<<dim3(D_ / 128, (B_ * T_) / 128, 3), 256, 0, stream>>>(
        xh, wqh, wkh, wvh, qh, kh, vth);

    flash_mfma<<<dim3(B_ * H_, 8, 1), 256, 0, stream>>>(qh, kh, vth, oh);

    gemm_wo<<<dim3(D_ / 128, (B_ * T_) / 128, 1), 256, 0, stream>>>(oh, woh, out);
}

// Round 6
// 279.348 us; speedup vs baseline: 1.0491x; 1.0491x over previous
//
#include <hip/hip_runtime.h>
#include <hip/hip_bf16.h>
#include <math.h>

#define B_ 4
#define T_ 2048
#define D_ 1024
#define H_ 16
#define HD_ 64

typedef _Float16 f16x8 __attribute__((ext_vector_type(8)));
typedef _Float16 f16x4 __attribute__((ext_vector_type(4)));
typedef float f32x4 __attribute__((ext_vector_type(4)));

// async global->LDS, 16 B per lane, dest = wave-uniform base + lane*16
__device__ __forceinline__ void gload_lds16(const _Float16* g, _Float16* l) {
    __builtin_amdgcn_global_load_lds(
        (const __attribute__((address_space(1))) void*)g,
        (__attribute__((address_space(3))) void*)l,
        16, 0, 0);
}

// ---------------------------------------------------------------------------
// Fused input + 4-weight fp32 -> fp16 cast, one launch.
// Work layout (all pow2, exact): [0, 2^21) -> x (NE/4 float4s),
// then 4 x 2^18 float4s for wq,wk,wv,wo.  12288 blocks x 256 thr.
// ---------------------------------------------------------------------------
__global__ __launch_bounds__(256) void castall(const float* __restrict__ x,
                                               const float* __restrict__ wq,
                                               const float* __restrict__ wk,
                                               const float* __restrict__ wv,
                                               const float* __restrict__ wo,
                                               _Float16* __restrict__ xh,
                                               _Float16* __restrict__ wqh,
                                               _Float16* __restrict__ wkh,
                                               _Float16* __restrict__ wvh,
                                               _Float16* __restrict__ woh) {
    const int gi = blockIdx.x * 256 + threadIdx.x;
    const float* in;
    _Float16* out;
    int off;
    if (gi < (1 << 21)) {
        in = x; out = xh; off = gi;
    } else {
        const int j = gi - (1 << 21);
        const int w = j >> 18;
        off = j & ((1 << 18) - 1);
        in  = (w == 0) ? wq : (w == 1 ? wk : (w == 2 ? wv : wo));
        out = (w == 0) ? wqh : (w == 1 ? wkh : (w == 2 ? wvh : woh));
    }
    const float4 v = ((const float4*)in)[off];
    f16x4 h = {(_Float16)v.x, (_Float16)v.y, (_Float16)v.z, (_Float16)v.w};
    ((f16x4*)out)[off] = h;
}

// ---------------------------------------------------------------------------
// Fused QKV GEMM + rmsnorm/rotary epilogue (m97 structure) + T1 XCD swizzle.
// Default XCD assignment (id%8) pins one weight col-panel per XCD but streams
// ALL of A through each XCD (16 MB >> 4 MB L2).  Chunked remap gives each XCD
// a contiguous 192-block range = 8 A-panels + 8 W-panels = 4 MB ~= L2, so A is
// read once per chunk and W stays L2-resident.  Bijective: 1536 % 8 == 0.
// z=0: rms+rotary+0.125*log2e -> qh ; z=1: rms+rotary -> kh ;
// z=2: plain -> vt transposed [b][h][d][T]
// ---------------------------------------------------------------------------
__global__ __launch_bounds__(256) void gemm_qkv(const _Float16* __restrict__ A,
                                                const _Float16* __restrict__ Wq,
                                                const _Float16* __restrict__ Wk,
                                                const _Float16* __restrict__ Wv,
                                                _Float16* __restrict__ qh,
                                                _Float16* __restrict__ kh,
                                                _Float16* __restrict__ vt) {
    constexpr int K = D_;
    // ---- XCD-chunked bijective remap: grid (8, 64, 3) = 1536 blocks ----
    const int id  = blockIdx.x + 8 * (blockIdx.y + 64 * blockIdx.z);
    const int nid = (id & 7) * 192 + (id >> 3);        // chunk = 1536/8
    const int bx  = nid & 7;
    const int rem = nid >> 3;
    const int by  = rem & 63;
    const int z   = rem >> 6;

    const _Float16* W = (z == 0) ? Wq : (z == 1 ? Wk : Wv);
    __shared__ _Float16 As[128 * 32];
    __shared__ _Float16 Bs[128 * 32];
    const int tid = threadIdx.x;
    const int lane = tid & 63, w = tid >> 6;
    const int col = lane & 15, quad = lane >> 4;
    const int wm = w >> 1, wn = w & 1;
    const int row0 = by * 128, col0 = bx * 128;
    const int sr = lane >> 2, sc = (lane & 3) * 8;

    f32x4 acc[4][4];
#pragma unroll
    for (int i = 0; i < 4; ++i)
#pragma unroll
        for (int j = 0; j < 4; ++j) acc[i][j] = (f32x4){0.f, 0.f, 0.f, 0.f};

    for (int kt = 0; kt < K / 32; ++kt) {
        const int k0 = kt * 32;
#pragma unroll
        for (int it = 0; it < 2; ++it) {
            const int rb = it * 64 + w * 16;
            gload_lds16(A + (size_t)(row0 + rb + sr) * K + k0 + sc, As + rb * 32);
            gload_lds16(W + (size_t)(col0 + rb + sr) * K + k0 + sc, Bs + rb * 32);
        }
        __syncthreads();
        f16x8 af[4], bf[4];
#pragma unroll
        for (int i = 0; i < 4; ++i) {
            af[i] = *(const f16x8*)&As[(wm * 64 + i * 16 + col) * 32 + quad * 8];
            bf[i] = *(const f16x8*)&Bs[(wn * 64 + i * 16 + col) * 32 + quad * 8];
        }
#pragma unroll
        for (int mi = 0; mi < 4; ++mi)
#pragma unroll
            for (int ni = 0; ni < 4; ++ni)
                acc[mi][ni] = __builtin_amdgcn_mfma_f32_16x16x32_f16(af[mi], bf[ni],
                                                                     acc[mi][ni], 0, 0, 0);
        __syncthreads();
    }

    if (z < 2) {
        _Float16* C = (z == 0) ? qh : kh;
        const float qscale = (z == 0) ? 0.18033688011112042f : 1.0f;  // 0.125*log2(e)
        const float fr = exp2f(-10.0f * (float)col * (1.0f / 15.0f));
#pragma unroll
        for (int mi = 0; mi < 4; ++mi) {
            float ssq[4];
#pragma unroll
            for (int r = 0; r < 4; ++r) {
                float t = 0.f;
#pragma unroll
                for (int ni = 0; ni < 4; ++ni) t += acc[mi][ni][r] * acc[mi][ni][r];
                ssq[r] = t;
            }
#pragma unroll
            for (int st = 1; st < 16; st <<= 1)
#pragma unroll
                for (int r = 0; r < 4; ++r) ssq[r] += __shfl_xor(ssq[r], st, 64);
            const int rowb = row0 + wm * 64 + mi * 16 + quad * 4;
#pragma unroll
            for (int r = 0; r < 4; ++r) {
                const float scl = rsqrtf(ssq[r] * (1.0f / 64.0f) + 1e-6f) * qscale;
                const int t = (rowb + r) & (T_ - 1);
                float s, c;
                sincosf((float)t * fr, &s, &c);
                const float x0 = acc[mi][0][r] * scl;
                const float x1 = acc[mi][1][r] * scl;
                const float x2 = acc[mi][2][r] * scl;
                const float x3 = acc[mi][3][r] * scl;
                const float y0 = fmaf(x0, c, x2 * s);
                const float y2 = fmaf(x2, c, -x0 * s);
                const size_t base = (size_t)(rowb + r) * D_ + col0 + wn * 64 + col;
                C[base + 0]  = (_Float16)y0;
                C[base + 16] = (_Float16)x1;
                C[base + 32] = (_Float16)y2;
                C[base + 48] = (_Float16)x3;
            }
        }
    } else {
        const int hh = bx * 2 + wn;
#pragma unroll
        for (int mi = 0; mi < 4; ++mi) {
            const int row = row0 + wm * 64 + mi * 16 + quad * 4;
            const int bb = row >> 11;
            const int t0m = row & (T_ - 1);
#pragma unroll
            for (int ni = 0; ni < 4; ++ni) {
                const int d = ni * 16 + col;
                f16x4 pk = {(_Float16)acc[mi][ni][0], (_Float16)acc[mi][ni][1],
                            (_Float16)acc[mi][ni][2], (_Float16)acc[mi][ni][3]};
                *(f16x4*)&vt[((size_t)(bb * H_ + hh) * HD_ + d) * T_ + t0m] = pk;
            }
        }
    }
}

// ---------------------------------------------------------------------------
// WO GEMM: out[M,N] = A[M,K] @ W[N,K]^T, fp16 in, fp32 out. m97 structure
// + T1 XCD-chunked swizzle (512 blocks, chunk 64: 8 A + 8 W panels / XCD).
// ---------------------------------------------------------------------------
__global__ __launch_bounds__(256) void gemm_wo(const _Float16* __restrict__ A,
                                               const _Float16* __restrict__ W,
                                               float* __restrict__ C) {
    constexpr int K = D_, N = D_;
    // ---- XCD-chunked bijective remap: grid (8, 64) = 512 blocks ----
    const int id  = blockIdx.x + 8 * blockIdx.y;
    const int nid = (id & 7) * 64 + (id >> 3);
    const int bx  = nid & 7;
    const int by  = nid >> 3;

    __shared__ _Float16 As[128 * 32];
    __shared__ _Float16 Bs[128 * 32];
    const int tid = threadIdx.x;
    const int lane = tid & 63, w = tid >> 6;
    const int col = lane & 15, quad = lane >> 4;
    const int wm = w >> 1, wn = w & 1;
    const int row0 = by * 128, col0 = bx * 128;
    const int sr = lane >> 2, sc = (lane & 3) * 8;

    f32x4 acc[4][4];
#pragma unroll
    for (int i = 0; i < 4; ++i)
#pragma unroll
        for (int j = 0; j < 4; ++j) acc[i][j] = (f32x4){0.f, 0.f, 0.f, 0.f};

    for (int kt = 0; kt < K / 32; ++kt) {
        const int k0 = kt * 32;
#pragma unroll
        for (int it = 0; it < 2; ++it) {
            const int rb = it * 64 + w * 16;
            gload_lds16(A + (size_t)(row0 + rb + sr) * K + k0 + sc, As + rb * 32);
            gload_lds16(W + (size_t)(col0 + rb + sr) * K + k0 + sc, Bs + rb * 32);
        }
        __syncthreads();
        f16x8 af[4], bf[4];
#pragma unroll
        for (int i = 0; i < 4; ++i) {
            af[i] = *(const f16x8*)&As[(wm * 64 + i * 16 + col) * 32 + quad * 8];
            bf[i] = *(const f16x8*)&Bs[(wn * 64 + i * 16 + col) * 32 + quad * 8];
        }
#pragma unroll
        for (int mi = 0; mi < 4; ++mi)
#pragma unroll
            for (int ni = 0; ni < 4; ++ni)
                acc[mi][ni] = __builtin_amdgcn_mfma_f32_16x16x32_f16(af[mi], bf[ni],
                                                                     acc[mi][ni], 0, 0, 0);
        __syncthreads();
    }
#pragma unroll
    for (int mi = 0; mi < 4; ++mi)
#pragma unroll
        for (int ni = 0; ni < 4; ++ni)
#pragma unroll
            for (int r = 0; r < 4; ++r)
                C[(size_t)(row0 + wm * 64 + mi * 16 + quad * 4 + r) * N +
                  col0 + wn * 64 + ni * 16 + col] = acc[mi][ni][r];
}

// ---------------------------------------------------------------------------
// MFMA flash attention (fp16 in/out). 512 thr = 8 waves, 128 q per block,
// wave w owns q rows [q0+16w, q0+16w+16). K-tiles of 64 keys.
// ROUND 6: REVERTED to the round-4 version (round-5 32q/wave regressed:
// 256 thr + 55 KB LDS halved occupancy 16->8 waves/CU; VALU softmax chain
// doubled per wave before each barrier. MfmaUtil 15.6 / VALUBusy 57.7
// showed latency/VALU regime, not LDS-read-bound).
// Double-buffered K/V staging; single vmcnt(0)+s_barrier per tile; Pl is
// wave-private; sched_barrier(0) fences around asm waits (rule #18);
// setprio around MFMA clusters.
// ---------------------------------------------------------------------------
#define LDP 88

__global__ __launch_bounds__(512) void flash_mfma(const _Float16* __restrict__ qh,
                                                  const _Float16* __restrict__ kh,
                                                  const _Float16* __restrict__ vt,
                                                  _Float16* __restrict__ o) {
    __shared__ _Float16 Kl[2][64 * 64];
    __shared__ _Float16 Vl[2][64 * 64];
    __shared__ _Float16 Pl[8][16 * LDP];
    const int tid = threadIdx.x;
    const int lane = tid & 63, w = tid >> 6;           // w in [0,8)
    const int col = lane & 15, quad = lane >> 4;
    const int bh = blockIdx.x, b = bh >> 4, h = bh & 15;
    const int srow = lane >> 3;                        // row-in-8 for staging
    const int schunk = (lane & 7) ^ srow;              // global-side swizzle
    const int sw = col & 7;                            // read-side swizzle key
    const int rstg = w * 8 + srow;                     // staged row (0..63)

    const _Float16* kbase = kh + ((size_t)b * T_ * H_ + (size_t)h) * HD_;
    const _Float16* vbase = vt + ((size_t)(b * H_ + h)) * (size_t)HD_ * T_;

    for (int phase = 0; phase < 2; ++phase) {
        const int qt = (phase == 0) ? (int)blockIdx.y : (15 - (int)blockIdx.y);
        const int q0 = qt * 128;

        // Q as B-operand: lane holds Q[q=q0+16w+col][d = quad*8+j (+32)]
        const int tq = q0 + w * 16 + col;
        const _Float16* qp = qh + ((size_t)(b * T_ + tq) * H_ + h) * HD_ + quad * 8;
        const f16x8 qB0 = *(const f16x8*)(qp);
        const f16x8 qB1 = *(const f16x8*)(qp + 32);

        f32x4 oa[4];
#pragma unroll
        for (int i = 0; i < 4; ++i) oa[i] = (f32x4){0.f, 0.f, 0.f, 0.f};
        float l_ = 0.f;  // per-lane partial denom for q = col

        const int nkt = 2 * qt + 2;

        // ---- prologue: stage tile 0 -> buf 0, full drain ----
        gload_lds16(kbase + (size_t)(0 + rstg) * H_ * HD_ + schunk * 8,
                    &Kl[0][(w * 8) * 64]);
        gload_lds16(vbase + (size_t)rstg * T_ + 0 + schunk * 8,
                    &Vl[0][(w * 8) * 64]);
        __builtin_amdgcn_sched_barrier(0);
        asm volatile("s_waitcnt vmcnt(0)" ::: "memory");
        __builtin_amdgcn_sched_barrier(0);
        __builtin_amdgcn_s_barrier();

        for (int kt = 0; kt < nkt; ++kt) {
            const int k0 = kt * 64;
            const int cur = kt & 1;

            // ---- issue next tile's stage early (hides under compute) ----
            if (kt + 1 < nkt) {
                gload_lds16(kbase + (size_t)(k0 + 64 + rstg) * H_ * HD_ + schunk * 8,
                            &Kl[cur ^ 1][(w * 8) * 64]);
                gload_lds16(vbase + (size_t)rstg * T_ + k0 + 64 + schunk * 8,
                            &Vl[cur ^ 1][(w * 8) * 64]);
            }

            // ---- S^T[key][q]: A = K rows, B = Q (in regs) ----
            f32x4 s[4];
            __builtin_amdgcn_s_setprio(1);
#pragma unroll
            for (int tn = 0; tn < 4; ++tn) {
                const _Float16* kp = &Kl[cur][(tn * 16 + col) * 64];
                const f16x8 kA0 = *(const f16x8*)(kp + ((quad ^ sw) << 3));
                const f16x8 kA1 = *(const f16x8*)(kp + (((quad | 4) ^ sw) << 3));
                f32x4 a = (f32x4){0.f, 0.f, 0.f, 0.f};
                a = __builtin_amdgcn_mfma_f32_16x16x32_f16(kA0, qB0, a, 0, 0, 0);
                a = __builtin_amdgcn_mfma_f32_16x16x32_f16(kA1, qB1, a, 0, 0, 0);
                s[tn] = a;
            }
            __builtin_amdgcn_s_setprio(0);

            // ---- causal mask: any key in tile beyond this wave's q rows ----
            if (k0 + 63 > q0 + w * 16) {
                const int qq = q0 + w * 16 + col;
#pragma unroll
                for (int tn = 0; tn < 4; ++tn)
#pragma unroll
                    for (int r = 0; r < 4; ++r) {
                        const int key = k0 + tn * 16 + quad * 4 + r;
                        if (key > qq) s[tn][r] = -1e30f;
                    }
            }

            // ---- p = exp2(s); l accumulate; packed P store (4x b64) ----
#pragma unroll
            for (int tn = 0; tn < 4; ++tn) {
                f16x4 pk;
#pragma unroll
                for (int r = 0; r < 4; ++r) {
                    const float p = exp2f(s[tn][r]);
                    l_ += p;
                    pk[r] = (_Float16)p;
                }
                *(f16x4*)&Pl[w][col * LDP + tn * 16 + quad * 4] = pk;
            }

            // ---- O[q][d] += P @ V (Pl[w] wave-private, no barrier) ----
            const f16x8 pA0 = *(const f16x8*)&Pl[w][col * LDP + quad * 8];
            const f16x8 pA1 = *(const f16x8*)&Pl[w][col * LDP + quad * 8 + 32];
            __builtin_amdgcn_s_setprio(1);
#pragma unroll
            for (int tn = 0; tn < 4; ++tn) {
                const _Float16* vp = &Vl[cur][(tn * 16 + col) * 64];
                const f16x8 vB0 = *(const f16x8*)(vp + ((quad ^ sw) << 3));
                const f16x8 vB1 = *(const f16x8*)(vp + (((quad | 4) ^ sw) << 3));
                oa[tn] = __builtin_amdgcn_mfma_f32_16x16x32_f16(pA0, vB0, oa[tn], 0, 0, 0);
                oa[tn] = __builtin_amdgcn_mfma_f32_16x16x32_f16(pA1, vB1, oa[tn], 0, 0, 0);
            }
            __builtin_amdgcn_s_setprio(0);

            // ---- single per-tile sync: next tile landed + all waves done ----
            __builtin_amdgcn_sched_barrier(0);
            asm volatile("s_waitcnt vmcnt(0)" ::: "memory");
            __builtin_amdgcn_sched_barrier(0);
            __builtin_amdgcn_s_barrier();
        }

        // ---- finish l (sum quads), redistribute to O rows, write ----
        l_ += __shfl_xor(l_, 16, 64);
        l_ += __shfl_xor(l_, 32, 64);
        const float linv = 1.0f / l_;
        float inv[4];
#pragma unroll
        for (int r = 0; r < 4; ++r) inv[r] = __shfl(linv, quad * 4 + r, 64);
#pragma unroll
        for (int tn = 0; tn < 4; ++tn)
#pragma unroll
            for (int r = 0; r < 4; ++r)
                o[((size_t)(b * T_ + q0 + w * 16 + quad * 4 + r) * H_ + h) * HD_ + tn * 16 + col] =
                    (_Float16)(oa[tn][r] * inv[r]);
    }
}

// ---------------------------------------------------------------------------
extern "C" void kernel_launch(void* const* d_in, const int* in_sizes, int n_in,
                              void* d_out, int out_size, void* d_ws, size_t ws_size,
                              hipStream_t stream) {
    const float* x  = (const float*)d_in[0];
    const float* wq = (const float*)d_in[1];
    const float* wk = (const float*)d_in[2];
    const float* wv = (const float*)d_in[3];
    const float* wo = (const float*)d_in[4];
    float* out = (float*)d_out;

    const size_t NE = (size_t)B_ * T_ * D_;   // 8,388,608
    const size_t WE = (size_t)D_ * D_;        // 1,048,576
    _Float16* xh  = (_Float16*)d_ws;
    _Float16* qh  = xh + NE;
    _Float16* kh  = qh + NE;
    _Float16* vth = kh + NE;
    _Float16* oh  = vth + NE;
    _Float16* wqh = oh + NE;
    _Float16* wkh = wqh + WE;
    _Float16* wvh = wkh + WE;
    _Float16* woh = wvh + WE;

    // fused casts: 2^21 (x) + 4 * 2^18 (weights) float4s = 12288 blocks
    castall<<<12288, 256, 0, stream>>>(x, wq, wk, wv, wo,
                                       xh, wqh, wkh, wvh, woh);

    gemm_qkv<<<dim3(D_ / 128, (B_ * T_) / 128, 3), 256, 0, stream>>>(
        xh, wqh, wkh, wvh, qh, kh, vth);

    flash_mfma<<<dim3(B_ * H_, 8, 1), 512, 0, stream>>>(qh, kh, vth, oh);

    gemm_wo<<<dim3(D_ / 128, (B_ * T_) / 128, 1), 256, 0, stream>>>(oh, woh, out);
}

// Round 8
// 257.721 us; speedup vs baseline: 1.1371x; 1.0839x over previous
//
#include <hip/hip_runtime.h>
#include <hip/hip_bf16.h>
#include <math.h>

#define B_ 4
#define T_ 2048
#define D_ 1024
#define H_ 16
#define HD_ 64

typedef _Float16 f16x8 __attribute__((ext_vector_type(8)));
typedef _Float16 f16x4 __attribute__((ext_vector_type(4)));
typedef __fp16 h16x2 __attribute__((ext_vector_type(2)));   // cvt_pkrtz native type
typedef float f32x4 __attribute__((ext_vector_type(4)));

// async global->LDS, 16 B per lane, dest = wave-uniform base + lane*16
__device__ __forceinline__ void gload_lds16(const _Float16* g, _Float16* l) {
    __builtin_amdgcn_global_load_lds(
        (const __attribute__((address_space(1))) void*)g,
        (__attribute__((address_space(3))) void*)l,
        16, 0, 0);
}

// ---------------------------------------------------------------------------
// Fused input + 4-weight fp32 -> fp16 cast, one launch.
// Work layout (all pow2, exact): [0, 2^21) -> x (NE/4 float4s),
// then 4 x 2^18 float4s for wq,wk,wv,wo.  12288 blocks x 256 thr.
// ---------------------------------------------------------------------------
__global__ __launch_bounds__(256) void castall(const float* __restrict__ x,
                                               const float* __restrict__ wq,
                                               const float* __restrict__ wk,
                                               const float* __restrict__ wv,
                                               const float* __restrict__ wo,
                                               _Float16* __restrict__ xh,
                                               _Float16* __restrict__ wqh,
                                               _Float16* __restrict__ wkh,
                                               _Float16* __restrict__ wvh,
                                               _Float16* __restrict__ woh) {
    const int gi = blockIdx.x * 256 + threadIdx.x;
    const float* in;
    _Float16* out;
    int off;
    if (gi < (1 << 21)) {
        in = x; out = xh; off = gi;
    } else {
        const int j = gi - (1 << 21);
        const int w = j >> 18;
        off = j & ((1 << 18) - 1);
        in  = (w == 0) ? wq : (w == 1 ? wk : (w == 2 ? wv : wo));
        out = (w == 0) ? wqh : (w == 1 ? wkh : (w == 2 ? wvh : woh));
    }
    const float4 v = ((const float4*)in)[off];
    f16x4 h = {(_Float16)v.x, (_Float16)v.y, (_Float16)v.z, (_Float16)v.w};
    ((f16x4*)out)[off] = h;
}

// ---------------------------------------------------------------------------
// Fused QKV GEMM + rmsnorm/rotary epilogue (m97 structure).
// XCD swizzle REVERTED (round 6: FETCH 135->49 MB but dur 84->89.5 — L2-fill
// traffic was not the bottleneck; remap broke one-W-panel-per-XCD residency).
// z=0: rms+rotary+0.125*log2e -> qh ; z=1: rms+rotary -> kh ;
// z=2: plain -> vt transposed [b][h][d][T]
// ---------------------------------------------------------------------------
__global__ __launch_bounds__(256) void gemm_qkv(const _Float16* __restrict__ A,
                                                const _Float16* __restrict__ Wq,
                                                const _Float16* __restrict__ Wk,
                                                const _Float16* __restrict__ Wv,
                                                _Float16* __restrict__ qh,
                                                _Float16* __restrict__ kh,
                                                _Float16* __restrict__ vt) {
    constexpr int K = D_;
    const int z = blockIdx.z;
    const _Float16* W = (z == 0) ? Wq : (z == 1 ? Wk : Wv);
    __shared__ _Float16 As[128 * 32];
    __shared__ _Float16 Bs[128 * 32];
    const int tid = threadIdx.x;
    const int lane = tid & 63, w = tid >> 6;
    const int col = lane & 15, quad = lane >> 4;
    const int wm = w >> 1, wn = w & 1;
    const int row0 = blockIdx.y * 128, col0 = blockIdx.x * 128;
    const int sr = lane >> 2, sc = (lane & 3) * 8;

    f32x4 acc[4][4];
#pragma unroll
    for (int i = 0; i < 4; ++i)
#pragma unroll
        for (int j = 0; j < 4; ++j) acc[i][j] = (f32x4){0.f, 0.f, 0.f, 0.f};

    for (int kt = 0; kt < K / 32; ++kt) {
        const int k0 = kt * 32;
#pragma unroll
        for (int it = 0; it < 2; ++it) {
            const int rb = it * 64 + w * 16;
            gload_lds16(A + (size_t)(row0 + rb + sr) * K + k0 + sc, As + rb * 32);
            gload_lds16(W + (size_t)(col0 + rb + sr) * K + k0 + sc, Bs + rb * 32);
        }
        __syncthreads();
        f16x8 af[4], bf[4];
#pragma unroll
        for (int i = 0; i < 4; ++i) {
            af[i] = *(const f16x8*)&As[(wm * 64 + i * 16 + col) * 32 + quad * 8];
            bf[i] = *(const f16x8*)&Bs[(wn * 64 + i * 16 + col) * 32 + quad * 8];
        }
#pragma unroll
        for (int mi = 0; mi < 4; ++mi)
#pragma unroll
            for (int ni = 0; ni < 4; ++ni)
                acc[mi][ni] = __builtin_amdgcn_mfma_f32_16x16x32_f16(af[mi], bf[ni],
                                                                     acc[mi][ni], 0, 0, 0);
        __syncthreads();
    }

    if (z < 2) {
        _Float16* C = (z == 0) ? qh : kh;
        const float qscale = (z == 0) ? 0.18033688011112042f : 1.0f;  // 0.125*log2(e)
        const float fr = exp2f(-10.0f * (float)col * (1.0f / 15.0f));
#pragma unroll
        for (int mi = 0; mi < 4; ++mi) {
            float ssq[4];
#pragma unroll
            for (int r = 0; r < 4; ++r) {
                float t = 0.f;
#pragma unroll
                for (int ni = 0; ni < 4; ++ni) t += acc[mi][ni][r] * acc[mi][ni][r];
                ssq[r] = t;
            }
#pragma unroll
            for (int st = 1; st < 16; st <<= 1)
#pragma unroll
                for (int r = 0; r < 4; ++r) ssq[r] += __shfl_xor(ssq[r], st, 64);
            const int rowb = row0 + wm * 64 + mi * 16 + quad * 4;
#pragma unroll
            for (int r = 0; r < 4; ++r) {
                const float scl = rsqrtf(ssq[r] * (1.0f / 64.0f) + 1e-6f) * qscale;
                const int t = (rowb + r) & (T_ - 1);
                float s, c;
                sincosf((float)t * fr, &s, &c);
                const float x0 = acc[mi][0][r] * scl;
                const float x1 = acc[mi][1][r] * scl;
                const float x2 = acc[mi][2][r] * scl;
                const float x3 = acc[mi][3][r] * scl;
                const float y0 = fmaf(x0, c, x2 * s);
                const float y2 = fmaf(x2, c, -x0 * s);
                const size_t base = (size_t)(rowb + r) * D_ + col0 + wn * 64 + col;
                C[base + 0]  = (_Float16)y0;
                C[base + 16] = (_Float16)x1;
                C[base + 32] = (_Float16)y2;
                C[base + 48] = (_Float16)x3;
            }
        }
    } else {
        const int hh = blockIdx.x * 2 + wn;
#pragma unroll
        for (int mi = 0; mi < 4; ++mi) {
            const int row = row0 + wm * 64 + mi * 16 + quad * 4;
            const int bb = row >> 11;
            const int t0m = row & (T_ - 1);
#pragma unroll
            for (int ni = 0; ni < 4; ++ni) {
                const int d = ni * 16 + col;
                f16x4 pk = {(_Float16)acc[mi][ni][0], (_Float16)acc[mi][ni][1],
                            (_Float16)acc[mi][ni][2], (_Float16)acc[mi][ni][3]};
                *(f16x4*)&vt[((size_t)(bb * H_ + hh) * HD_ + d) * T_ + t0m] = pk;
            }
        }
    }
}

// ---------------------------------------------------------------------------
// WO GEMM: out[M,N] = A[M,K] @ W[N,K]^T, fp16 in, fp32 out. m97 structure.
// ---------------------------------------------------------------------------
__global__ __launch_bounds__(256) void gemm_wo(const _Float16* __restrict__ A,
                                               const _Float16* __restrict__ W,
                                               float* __restrict__ C) {
    constexpr int K = D_, N = D_;
    __shared__ _Float16 As[128 * 32];
    __shared__ _Float16 Bs[128 * 32];
    const int tid = threadIdx.x;
    const int lane = tid & 63, w = tid >> 6;
    const int col = lane & 15, quad = lane >> 4;
    const int wm = w >> 1, wn = w & 1;
    const int row0 = blockIdx.y * 128, col0 = blockIdx.x * 128;
    const int sr = lane >> 2, sc = (lane & 3) * 8;

    f32x4 acc[4][4];
#pragma unroll
    for (int i = 0; i < 4; ++i)
#pragma unroll
        for (int j = 0; j < 4; ++j) acc[i][j] = (f32x4){0.f, 0.f, 0.f, 0.f};

    for (int kt = 0; kt < K / 32; ++kt) {
        const int k0 = kt * 32;
#pragma unroll
        for (int it = 0; it < 2; ++it) {
            const int rb = it * 64 + w * 16;
            gload_lds16(A + (size_t)(row0 + rb + sr) * K + k0 + sc, As + rb * 32);
            gload_lds16(W + (size_t)(col0 + rb + sr) * K + k0 + sc, Bs + rb * 32);
        }
        __syncthreads();
        f16x8 af[4], bf[4];
#pragma unroll
        for (int i = 0; i < 4; ++i) {
            af[i] = *(const f16x8*)&As[(wm * 64 + i * 16 + col) * 32 + quad * 8];
            bf[i] = *(const f16x8*)&Bs[(wn * 64 + i * 16 + col) * 32 + quad * 8];
        }
#pragma unroll
        for (int mi = 0; mi < 4; ++mi)
#pragma unroll
            for (int ni = 0; ni < 4; ++ni)
                acc[mi][ni] = __builtin_amdgcn_mfma_f32_16x16x32_f16(af[mi], bf[ni],
                                                                     acc[mi][ni], 0, 0, 0);
        __syncthreads();
    }
#pragma unroll
    for (int mi = 0; mi < 4; ++mi)
#pragma unroll
        for (int ni = 0; ni < 4; ++ni)
#pragma unroll
            for (int r = 0; r < 4; ++r)
                C[(size_t)(row0 + wm * 64 + mi * 16 + quad * 4 + r) * N +
                  col0 + wn * 64 + ni * 16 + col] = acc[mi][ni][r];
}

// ---------------------------------------------------------------------------
// MFMA flash attention (fp16 in/out). 512 thr = 8 waves, 128 q per block,
// wave w owns q rows [q0+16w, q0+16w+16). K-tiles of 64 keys.
// ROUND 8 (VALU diet, fixed cvt_pkrtz typing — flash is VALU-bound:
// VALUBusy 57.7 / MfmaUtil 15.6):
//  1. exp2f -> __builtin_amdgcn_exp2f (single v_exp_f32).
//  2. f32->f16 P-packing via v_cvt_pkrtz (native __fp16x2 return type,
//     reinterpreted through a union to the packed f16x4 LDS store).
//  3. Fully-masked-tile compute skip: wave w needs no tile with
//     k0 > q0+16w+15 (staging + barriers stay uniform across waves).
// Dbuf staging + single vmcnt(0)+s_barrier per tile retained (round 4).
// ---------------------------------------------------------------------------
#define LDP 88

__global__ __launch_bounds__(512) void flash_mfma(const _Float16* __restrict__ qh,
                                                  const _Float16* __restrict__ kh,
                                                  const _Float16* __restrict__ vt,
                                                  _Float16* __restrict__ o) {
    __shared__ _Float16 Kl[2][64 * 64];
    __shared__ _Float16 Vl[2][64 * 64];
    __shared__ _Float16 Pl[8][16 * LDP];
    const int tid = threadIdx.x;
    const int lane = tid & 63, w = tid >> 6;           // w in [0,8)
    const int col = lane & 15, quad = lane >> 4;
    const int bh = blockIdx.x, b = bh >> 4, h = bh & 15;
    const int srow = lane >> 3;                        // row-in-8 for staging
    const int schunk = (lane & 7) ^ srow;              // global-side swizzle
    const int sw = col & 7;                            // read-side swizzle key
    const int rstg = w * 8 + srow;                     // staged row (0..63)

    const _Float16* kbase = kh + ((size_t)b * T_ * H_ + (size_t)h) * HD_;
    const _Float16* vbase = vt + ((size_t)(b * H_ + h)) * (size_t)HD_ * T_;

    for (int phase = 0; phase < 2; ++phase) {
        const int qt = (phase == 0) ? (int)blockIdx.y : (15 - (int)blockIdx.y);
        const int q0 = qt * 128;

        // Q as B-operand: lane holds Q[q=q0+16w+col][d = quad*8+j (+32)]
        const int tq = q0 + w * 16 + col;
        const _Float16* qp = qh + ((size_t)(b * T_ + tq) * H_ + h) * HD_ + quad * 8;
        const f16x8 qB0 = *(const f16x8*)(qp);
        const f16x8 qB1 = *(const f16x8*)(qp + 32);

        f32x4 oa[4];
#pragma unroll
        for (int i = 0; i < 4; ++i) oa[i] = (f32x4){0.f, 0.f, 0.f, 0.f};
        float l_ = 0.f;  // per-lane partial denom for q = col

        const int nkt = 2 * qt + 2;
        const int qmax = q0 + w * 16 + 15;   // this wave's largest q row

        // ---- prologue: stage tile 0 -> buf 0, full drain ----
        gload_lds16(kbase + (size_t)(0 + rstg) * H_ * HD_ + schunk * 8,
                    &Kl[0][(w * 8) * 64]);
        gload_lds16(vbase + (size_t)rstg * T_ + 0 + schunk * 8,
                    &Vl[0][(w * 8) * 64]);
        __builtin_amdgcn_sched_barrier(0);
        asm volatile("s_waitcnt vmcnt(0)" ::: "memory");
        __builtin_amdgcn_sched_barrier(0);
        __builtin_amdgcn_s_barrier();

        for (int kt = 0; kt < nkt; ++kt) {
            const int k0 = kt * 64;
            const int cur = kt & 1;

            // ---- issue next tile's stage early (hides under compute) ----
            if (kt + 1 < nkt) {
                gload_lds16(kbase + (size_t)(k0 + 64 + rstg) * H_ * HD_ + schunk * 8,
                            &Kl[cur ^ 1][(w * 8) * 64]);
                gload_lds16(vbase + (size_t)rstg * T_ + k0 + 64 + schunk * 8,
                            &Vl[cur ^ 1][(w * 8) * 64]);
            }

            // ---- fully-masked tile for this wave: skip compute entirely ----
            if (k0 <= qmax) {
                // ---- S^T[key][q]: A = K rows, B = Q (in regs) ----
                f32x4 s[4];
                __builtin_amdgcn_s_setprio(1);
#pragma unroll
                for (int tn = 0; tn < 4; ++tn) {
                    const _Float16* kp = &Kl[cur][(tn * 16 + col) * 64];
                    const f16x8 kA0 = *(const f16x8*)(kp + ((quad ^ sw) << 3));
                    const f16x8 kA1 = *(const f16x8*)(kp + (((quad | 4) ^ sw) << 3));
                    f32x4 a = (f32x4){0.f, 0.f, 0.f, 0.f};
                    a = __builtin_amdgcn_mfma_f32_16x16x32_f16(kA0, qB0, a, 0, 0, 0);
                    a = __builtin_amdgcn_mfma_f32_16x16x32_f16(kA1, qB1, a, 0, 0, 0);
                    s[tn] = a;
                }
                __builtin_amdgcn_s_setprio(0);

                // ---- causal mask: any key in tile beyond this wave's q rows ----
                if (k0 + 63 > q0 + w * 16) {
                    const int qq = q0 + w * 16 + col;
#pragma unroll
                    for (int tn = 0; tn < 4; ++tn)
#pragma unroll
                        for (int r = 0; r < 4; ++r) {
                            const int key = k0 + tn * 16 + quad * 4 + r;
                            if (key > qq) s[tn][r] = -1e30f;
                        }
                }

                // ---- p = exp2(s) [native], l accumulate, packed P store ----
#pragma unroll
                for (int tn = 0; tn < 4; ++tn) {
                    float p0 = __builtin_amdgcn_exp2f(s[tn][0]);
                    float p1 = __builtin_amdgcn_exp2f(s[tn][1]);
                    float p2 = __builtin_amdgcn_exp2f(s[tn][2]);
                    float p3 = __builtin_amdgcn_exp2f(s[tn][3]);
                    l_ += (p0 + p1) + (p2 + p3);
                    union { f16x4 v; h16x2 h[2]; } u;
                    u.h[0] = __builtin_amdgcn_cvt_pkrtz(p0, p1);
                    u.h[1] = __builtin_amdgcn_cvt_pkrtz(p2, p3);
                    *(f16x4*)&Pl[w][col * LDP + tn * 16 + quad * 4] = u.v;
                }

                // ---- O[q][d] += P @ V (Pl[w] wave-private, no barrier) ----
                const f16x8 pA0 = *(const f16x8*)&Pl[w][col * LDP + quad * 8];
                const f16x8 pA1 = *(const f16x8*)&Pl[w][col * LDP + quad * 8 + 32];
                __builtin_amdgcn_s_setprio(1);
#pragma unroll
                for (int tn = 0; tn < 4; ++tn) {
                    const _Float16* vp = &Vl[cur][(tn * 16 + col) * 64];
                    const f16x8 vB0 = *(const f16x8*)(vp + ((quad ^ sw) << 3));
                    const f16x8 vB1 = *(const f16x8*)(vp + (((quad | 4) ^ sw) << 3));
                    oa[tn] = __builtin_amdgcn_mfma_f32_16x16x32_f16(pA0, vB0, oa[tn], 0, 0, 0);
                    oa[tn] = __builtin_amdgcn_mfma_f32_16x16x32_f16(pA1, vB1, oa[tn], 0, 0, 0);
                }
                __builtin_amdgcn_s_setprio(0);
            }

            // ---- single per-tile sync: next tile landed + all waves done ----
            __builtin_amdgcn_sched_barrier(0);
            asm volatile("s_waitcnt vmcnt(0)" ::: "memory");
            __builtin_amdgcn_sched_barrier(0);
            __builtin_amdgcn_s_barrier();
        }

        // ---- finish l (sum quads), redistribute to O rows, write ----
        l_ += __shfl_xor(l_, 16, 64);
        l_ += __shfl_xor(l_, 32, 64);
        const float linv = 1.0f / l_;
        float inv[4];
#pragma unroll
        for (int r = 0; r < 4; ++r) inv[r] = __shfl(linv, quad * 4 + r, 64);
#pragma unroll
        for (int tn = 0; tn < 4; ++tn)
#pragma unroll
            for (int r = 0; r < 4; ++r)
                o[((size_t)(b * T_ + q0 + w * 16 + quad * 4 + r) * H_ + h) * HD_ + tn * 16 + col] =
                    (_Float16)(oa[tn][r] * inv[r]);
    }
}

// ---------------------------------------------------------------------------
extern "C" void kernel_launch(void* const* d_in, const int* in_sizes, int n_in,
                              void* d_out, int out_size, void* d_ws, size_t ws_size,
                              hipStream_t stream) {
    const float* x  = (const float*)d_in[0];
    const float* wq = (const float*)d_in[1];
    const float* wk = (const float*)d_in[2];
    const float* wv = (const float*)d_in[3];
    const float* wo = (const float*)d_in[4];
    float* out = (float*)d_out;

    const size_t NE = (size_t)B_ * T_ * D_;   // 8,388,608
    const size_t WE = (size_t)D_ * D_;        // 1,048,576
    _Float16* xh  = (_Float16*)d_ws;
    _Float16* qh  = xh + NE;
    _Float16* kh  = qh + NE;
    _Float16* vth = kh + NE;
    _Float16* oh  = vth + NE;
    _Float16* wqh = oh + NE;
    _Float16* wkh = wqh + WE;
    _Float16* wvh = wkh + WE;
    _Float16* woh = wvh + WE;

    // fused casts: 2^21 (x) + 4 * 2^18 (weights) float4s = 12288 blocks
    castall<<<12288, 256, 0, stream>>>(x, wq, wk, wv, wo,
                                       xh, wqh, wkh, wvh, woh);

    gemm_qkv<<<dim3(D_ / 128, (B_ * T_) / 128, 3), 256, 0, stream>>>(
        xh, wqh, wkh, wvh, qh, kh, vth);

    flash_mfma<<<dim3(B_ * H_, 8, 1), 512, 0, stream>>>(qh, kh, vth, oh);

    gemm_wo<<<dim3(D_ / 128, (B_ * T_) / 128, 1), 256, 0, stream>>>(oh, woh, out);
}